// Round 5
// baseline (113.566 us; speedup 1.0000x reference)
//
#include <hip/hip_runtime.h>
#include <cmath>

// Problem constants (fixed by setup_inputs)
#define BB 32
#define EE 256
#define NC 1024
#define NF 4096
#define TOKSTRIDE 5120   // Nc+Nf rows per batch
#define IMG 256

// Shared staging: 64 rows x 256 floats into LDS, row pitch 260 floats,
// f4-column XOR-swizzled by (row>>1)&7 so compute-phase row-strided
// ds_read_b128 hits the uniform bank floor.
__device__ __forceinline__ void stage64(const float* __restrict__ src,
                                        float* __restrict__ Xs, int tid) {
    #pragma unroll
    for (int i = 0; i < 16; ++i) {
        int f  = i * 256 + tid;          // f4 index within 64x64
        int r  = f >> 6;
        int c4 = f & 63;
        float4 v = *reinterpret_cast<const float4*>(src + (size_t)r * EE + c4 * 4);
        int c4s = c4 ^ ((r >> 1) & 7);
        *reinterpret_cast<float4*>(&Xs[r * 260 + c4s * 4]) = v;
    }
    __syncthreads();
}

// ---------------- K1: coarse GEMM -> coarse image (pre-conv) ----------------
// Tile: 64 tokens. Thread = (rs: 2 rows, cg: 16 of 64 cols, kh: K half).
__global__ __launch_bounds__(256) void k_coarse(const float* __restrict__ tokens,
                                                const float* __restrict__ Wc,
                                                const float* __restrict__ bc,
                                                float* __restrict__ coarse_img) {
    __shared__ float Xs[64 * 260];
    const int tid = threadIdx.x;
    const int b  = blockIdx.x >> 4;
    const int t0 = (blockIdx.x & 15) * 64;

    stage64(tokens + ((size_t)b * TOKSTRIDE + t0) * EE, Xs, tid);

    const int rs = tid >> 3;             // 0..31 (row pair)
    const int cg = (tid >> 1) & 3;       // col group (16 cols)
    const int kh = tid & 1;              // K half
    const int row0 = rs * 2;
    const int c0   = cg * 16;
    const int kq0  = kh * 32;            // f4 window: 32 f4 = 128 k
    const int swz  = rs & 7;

    float acc[2][16];
    #pragma unroll
    for (int r = 0; r < 2; ++r)
        #pragma unroll
        for (int c = 0; c < 16; ++c) acc[r][c] = 0.f;

    #pragma unroll 4
    for (int q = 0; q < 32; ++q) {
        const int kq = kq0 + q;
        float4 x0 = *reinterpret_cast<const float4*>(&Xs[row0 * 260       + (kq ^ swz) * 4]);
        float4 x1 = *reinterpret_cast<const float4*>(&Xs[(row0 + 1) * 260 + (kq ^ swz) * 4]);
        #pragma unroll
        for (int kk = 0; kk < 4; ++kk) {
            const float xv0 = (&x0.x)[kk];
            const float xv1 = (&x1.x)[kk];
            const float* wrow = Wc + (size_t)(kq * 4 + kk) * 64 + c0;
            #pragma unroll
            for (int c = 0; c < 4; ++c) {
                float4 w = *reinterpret_cast<const float4*>(wrow + c * 4);
                acc[0][c*4+0] = fmaf(xv0, w.x, acc[0][c*4+0]);
                acc[0][c*4+1] = fmaf(xv0, w.y, acc[0][c*4+1]);
                acc[0][c*4+2] = fmaf(xv0, w.z, acc[0][c*4+2]);
                acc[0][c*4+3] = fmaf(xv0, w.w, acc[0][c*4+3]);
                acc[1][c*4+0] = fmaf(xv1, w.x, acc[1][c*4+0]);
                acc[1][c*4+1] = fmaf(xv1, w.y, acc[1][c*4+1]);
                acc[1][c*4+2] = fmaf(xv1, w.z, acc[1][c*4+2]);
                acc[1][c*4+3] = fmaf(xv1, w.w, acc[1][c*4+3]);
            }
        }
    }

    // combine K halves (partner lane differs in bit 0)
    #pragma unroll
    for (int r = 0; r < 2; ++r)
        #pragma unroll
        for (int c = 0; c < 16; ++c)
            acc[r][c] += __shfl_xor(acc[r][c], 1, 64);

    if (kh == 0) {
        #pragma unroll
        for (int r = 0; r < 2; ++r) {
            const int tg = t0 + row0 + r;
            const int hc = tg >> 5, wc = tg & 31;
            #pragma unroll
            for (int half = 0; half < 2; ++half) {     // two patch rows per col group
                const int ph = cg * 2 + half;
                float* base = coarse_img + (size_t)b * 65536 + (hc * 8 + ph) * 256 + wc * 8;
                float4 o0 = make_float4(acc[r][half*8+0] + bc[c0 + half*8 + 0],
                                        acc[r][half*8+1] + bc[c0 + half*8 + 1],
                                        acc[r][half*8+2] + bc[c0 + half*8 + 2],
                                        acc[r][half*8+3] + bc[c0 + half*8 + 3]);
                float4 o1 = make_float4(acc[r][half*8+4] + bc[c0 + half*8 + 4],
                                        acc[r][half*8+5] + bc[c0 + half*8 + 5],
                                        acc[r][half*8+6] + bc[c0 + half*8 + 6],
                                        acc[r][half*8+7] + bc[c0 + half*8 + 7]);
                *reinterpret_cast<float4*>(base + 0) = o0;
                *reinterpret_cast<float4*>(base + 4) = o1;
            }
        }
    }
}

// ---------------- K2: per-batch inclusive cumsum of mask ----------------
__global__ __launch_bounds__(256) void k_scan(const int* __restrict__ mask,
                                              int* __restrict__ cum) {
    __shared__ int sums[256];
    const int b = blockIdx.x;
    const int tid = threadIdx.x;
    const int* m = mask + b * NF;

    int loc[16];
    int s = 0;
    #pragma unroll
    for (int i = 0; i < 16; ++i) { int v = (m[tid*16 + i] != 0) ? 1 : 0; s += v; loc[i] = s; }
    sums[tid] = s;
    __syncthreads();

    for (int off = 1; off < 256; off <<= 1) {
        int v = sums[tid];
        int add = (tid >= off) ? sums[tid - off] : 0;
        __syncthreads();
        sums[tid] = v + add;
        __syncthreads();
    }
    int excl = sums[tid] - s;
    #pragma unroll
    for (int i = 0; i < 16; ++i) cum[b*NF + tid*16 + i] = excl + loc[i];
}

// ---------------- K3: dense fine GEMM over compacted rows ----------------
// Tile: 64 rows. Thread = (rs: 2 rows, all 16 cols, kh3: 1/8 of K).
__global__ __launch_bounds__(256) void k_gemm(const float* __restrict__ tokens,
                                              const int* __restrict__ cum,
                                              const float* __restrict__ Wf,
                                              const float* __restrict__ bf,
                                              float* __restrict__ patch) {
    const int b  = blockIdx.x >> 6;            // 64 tiles/batch
    const int r0 = (blockIdx.x & 63) * 64;
    const int cnt = cum[b*NF + NF - 1];
    if (r0 >= cnt) return;

    __shared__ float Xs[64 * 260];
    const int tid = threadIdx.x;
    stage64(tokens + ((size_t)b * TOKSTRIDE + NC + r0) * EE, Xs, tid);

    const int rl  = tid & 7;
    const int kh3 = (tid >> 3) & 7;            // K eighth
    const int rh  = tid >> 6;
    const int rs  = rh * 8 + rl;               // 0..31 (row pair)
    const int row0 = rs * 2;
    const int kq0  = kh3 * 8;                  // 8 f4 = 32 k
    const int swz  = rs & 7;

    float acc[2][16];
    #pragma unroll
    for (int r = 0; r < 2; ++r)
        #pragma unroll
        for (int c = 0; c < 16; ++c) acc[r][c] = 0.f;

    #pragma unroll
    for (int q = 0; q < 8; ++q) {
        const int kq = kq0 + q;
        float4 x0 = *reinterpret_cast<const float4*>(&Xs[row0 * 260       + (kq ^ swz) * 4]);
        float4 x1 = *reinterpret_cast<const float4*>(&Xs[(row0 + 1) * 260 + (kq ^ swz) * 4]);
        #pragma unroll
        for (int kk = 0; kk < 4; ++kk) {
            const float xv0 = (&x0.x)[kk];
            const float xv1 = (&x1.x)[kk];
            const float* wrow = Wf + (size_t)(kq * 4 + kk) * 16;
            #pragma unroll
            for (int c = 0; c < 4; ++c) {
                float4 w = *reinterpret_cast<const float4*>(wrow + c * 4);
                acc[0][c*4+0] = fmaf(xv0, w.x, acc[0][c*4+0]);
                acc[0][c*4+1] = fmaf(xv0, w.y, acc[0][c*4+1]);
                acc[0][c*4+2] = fmaf(xv0, w.z, acc[0][c*4+2]);
                acc[0][c*4+3] = fmaf(xv0, w.w, acc[0][c*4+3]);
                acc[1][c*4+0] = fmaf(xv1, w.x, acc[1][c*4+0]);
                acc[1][c*4+1] = fmaf(xv1, w.y, acc[1][c*4+1]);
                acc[1][c*4+2] = fmaf(xv1, w.z, acc[1][c*4+2]);
                acc[1][c*4+3] = fmaf(xv1, w.w, acc[1][c*4+3]);
            }
        }
    }

    // reduce across the 8 K-groups (lane bits 3..5)
    #pragma unroll
    for (int r = 0; r < 2; ++r)
        #pragma unroll
        for (int c = 0; c < 16; ++c) {
            float v = acc[r][c];
            v += __shfl_xor(v, 8, 64);
            v += __shfl_xor(v, 16, 64);
            v += __shfl_xor(v, 32, 64);
            acc[r][c] = v;
        }

    if (kh3 == 0) {
        #pragma unroll
        for (int r = 0; r < 2; ++r) {
            const int row = r0 + row0 + r;
            float* dst = patch + ((size_t)b * NF + row) * 16;
            #pragma unroll
            for (int c = 0; c < 4; ++c) {
                float4 o = make_float4(acc[r][c*4+0] + bf[c*4+0],
                                       acc[r][c*4+1] + bf[c*4+1],
                                       acc[r][c*4+2] + bf[c*4+2],
                                       acc[r][c*4+3] + bf[c*4+3]);
                *reinterpret_cast<float4*>(dst + c * 4) = o;
            }
        }
    }
}

// ---------------- K4: fused scatter + conv + blend + downsample ----------------
struct InterpArgs { int i0[32]; int i1[32]; float fr[32]; };

__global__ __launch_bounds__(128) void k_out(const float* __restrict__ coarse_img,
                                             const float* __restrict__ patch,
                                             const int* __restrict__ mask,
                                             const int* __restrict__ cum,
                                             const float* __restrict__ noise,
                                             const float* __restrict__ convw,
                                             float* __restrict__ out,
                                             InterpArgs ia) {
    const int tid = blockIdx.x * 128 + threadIdx.x;   // 32768
    const int b = tid >> 10;
    const int p = (tid >> 5) & 31;
    const int q = tid & 31;

    float kk[9];
    #pragma unroll
    for (int i = 0; i < 9; ++i) kk[i] = convw[i];

    const int   hs[2]  = { ia.i0[p], ia.i1[p] };
    const float fh     = ia.fr[p];
    const float wh[2]  = { 1.f - fh, fh };
    const int   wsx[2] = { ia.i0[q], ia.i1[q] };
    const float fw     = ia.fr[q];
    const float ww[2]  = { 1.f - fw, fw };

    const float* cimg = coarse_img + (size_t)b*65536;
    const float* nimg = noise      + (size_t)b*65536;

    float acc = 0.f;
    #pragma unroll
    for (int a = 0; a < 2; ++a) {
        #pragma unroll
        for (int c = 0; c < 2; ++c) {
            const int h = hs[a], w = wsx[c];
            float conv = 0.f;
            #pragma unroll
            for (int dh = -1; dh <= 1; ++dh) {
                #pragma unroll
                for (int dw = -1; dw <= 1; ++dw) {
                    int hh = h + dh, wp = w + dw;
                    float v = (hh >= 0 && hh < IMG && wp >= 0 && wp < IMG)
                              ? cimg[hh*IMG + wp] : 0.f;
                    conv = fmaf(v, kk[(dh+1)*3 + (dw+1)], conv);
                }
            }
            const int j = (h >> 2) * 64 + (w >> 2);
            float fv = 0.f;
            if (mask[b*NF + j] != 0) {
                int rk  = cum[b*NF + j] - 1;
                int col = (h & 3) * 4 + (w & 3);
                fv = patch[((size_t)b*NF + rk)*16 + col];
            }
            float s = 1.f / (1.f + expf(-0.1f * nimg[h*IMG + w]));
            acc += wh[a] * ww[c] * (conv * (1.f - s) + fv * s);
        }
    }
    out[tid] = acc;
}

extern "C" void kernel_launch(void* const* d_in, const int* in_sizes, int n_in,
                              void* d_out, int out_size, void* d_ws, size_t ws_size,
                              hipStream_t stream) {
    const float* tokens = (const float*)d_in[0];
    const int*   mask   = (const int*)  d_in[1];
    const float* Wc     = (const float*)d_in[2];
    const float* bc     = (const float*)d_in[3];
    const float* Wf     = (const float*)d_in[4];
    const float* bf     = (const float*)d_in[5];
    const float* convw  = (const float*)d_in[6];
    const float* noise  = (const float*)d_in[7];

    float* ws = (float*)d_ws;
    float* coarse_img = ws;                               // 32*65536 floats
    float* patch      = ws + (size_t)BB*65536;            // 32*4096*16 floats
    int*   cum        = (int*)(ws + (size_t)2*BB*65536);  // 32*4096 ints

    k_scan  <<<32,   256, 0, stream>>>(mask, cum);
    k_coarse<<<512,  256, 0, stream>>>(tokens, Wc, bc, coarse_img);
    k_gemm  <<<2048, 256, 0, stream>>>(tokens, cum, Wf, bf, patch);

    InterpArgs ia;
    for (int p = 0; p < 32; ++p) {
        double pos = (double)p * 255.0 / 31.0;
        int i0 = (int)floor(pos);
        int i1 = (i0 + 1 < 256) ? i0 + 1 : 255;
        ia.i0[p] = i0; ia.i1[p] = i1; ia.fr[p] = (float)(pos - (double)i0);
    }
    k_out<<<256, 128, 0, stream>>>(coarse_img, patch, mask, cum, noise, convw,
                                   (float*)d_out, ia);
}

// Round 7
// 55.013 us; speedup vs baseline: 2.0644x; 2.0644x over previous
//
#include <hip/hip_runtime.h>
#include <cmath>

// Problem constants (fixed by setup_inputs)
#define BB 32
#define EE 256
#define NC 1024
#define NF 4096
#define TOKSTRIDE 5120   // Nc+Nf rows per batch
#define IMG 256

typedef _Float16 f16x8 __attribute__((ext_vector_type(8)));
typedef float    f32x4 __attribute__((ext_vector_type(4)));

// ---------------- K1: coarse GEMM -> coarse image (round-2 form) ----------------
__global__ __launch_bounds__(256) void k_coarse(const float* __restrict__ tokens,
                                                const float* __restrict__ Wc,
                                                const float* __restrict__ bc,
                                                float* __restrict__ coarse_img) {
    __shared__ float tok[32][260];
    const int tid = threadIdx.x;
    const int tokbase = blockIdx.x * 32;
    const int b  = tokbase >> 10;
    const int t0 = tokbase & 1023;
    const float* src = tokens + ((size_t)b * TOKSTRIDE + t0) * EE;

    #pragma unroll
    for (int i = 0; i < 8; ++i) {
        int f = i * 1024 + tid * 4;
        int r = f >> 8, c = f & 255;
        float4 v = *reinterpret_cast<const float4*>(src + f);
        *reinterpret_cast<float4*>(&tok[r][c]) = v;
    }
    __syncthreads();

    const int wave = tid >> 6;
    const int lane = tid & 63;
    float acc[8] = {0.f,0.f,0.f,0.f,0.f,0.f,0.f,0.f};

    for (int k = 0; k < 256; k += 4) {
        float w0 = Wc[(k+0)*64 + lane];
        float w1 = Wc[(k+1)*64 + lane];
        float w2 = Wc[(k+2)*64 + lane];
        float w3 = Wc[(k+3)*64 + lane];
        #pragma unroll
        for (int t = 0; t < 8; ++t) {
            const float* tp = &tok[wave*8 + t][k];
            float4 t4 = *reinterpret_cast<const float4*>(tp);
            acc[t] = fmaf(t4.x, w0, acc[t]);
            acc[t] = fmaf(t4.y, w1, acc[t]);
            acc[t] = fmaf(t4.z, w2, acc[t]);
            acc[t] = fmaf(t4.w, w3, acc[t]);
        }
    }

    const float bias = bc[lane];
    const int ph = lane >> 3, pw = lane & 7;
    #pragma unroll
    for (int t = 0; t < 8; ++t) {
        int tg = t0 + wave*8 + t;
        int hc = tg >> 5, wc = tg & 31;
        int h = hc*8 + ph, w = wc*8 + pw;
        coarse_img[(size_t)b*65536 + h*256 + w] = acc[t] + bias;
    }
}

// ---------------- K2: per-batch inclusive cumsum of mask ----------------
__global__ __launch_bounds__(256) void k_scan(const int* __restrict__ mask,
                                              int* __restrict__ cum) {
    __shared__ int sums[256];
    const int b = blockIdx.x;
    const int tid = threadIdx.x;
    const int* m = mask + b * NF;

    int loc[16];
    int s = 0;
    #pragma unroll
    for (int i = 0; i < 16; ++i) { int v = (m[tid*16 + i] != 0) ? 1 : 0; s += v; loc[i] = s; }
    sums[tid] = s;
    __syncthreads();

    for (int off = 1; off < 256; off <<= 1) {
        int v = sums[tid];
        int add = (tid >= off) ? sums[tid - off] : 0;
        __syncthreads();
        sums[tid] = v + add;
        __syncthreads();
    }
    int excl = sums[tid] - s;
    #pragma unroll
    for (int i = 0; i < 16; ++i) cum[b*NF + tid*16 + i] = excl + loc[i];
}

// ---------------- K3: fine GEMM via f16 MFMA over compacted rows ----------------
// patch[b][row][16] = fine_tokens[b][row] @ Wf + bf, rows < cnt[b] meaningful.
// 64-row tile, 4 waves x (16 rows x 16 cols), K=256 = 8 chained mfma_16x16x32.
// LDS swizzle: 16B-chunk index XORed with (row&7) on BOTH write and read
// (same involution both sides — round-6 bug was applying it inconsistently).
__global__ __launch_bounds__(256) void k_gemm(const float* __restrict__ tokens,
                                              const int* __restrict__ cum,
                                              const float* __restrict__ Wf,
                                              const float* __restrict__ bf,
                                              float* __restrict__ patch) {
    const int b  = blockIdx.x >> 6;            // 64 tiles/batch
    const int r0 = (blockIdx.x & 63) * 64;
    const int cnt = cum[b*NF + NF - 1];
    if (r0 >= cnt) return;

    __shared__ _Float16 Xs[64 * 256];          // 32 KB

    const int tid  = threadIdx.x;
    const int lane = tid & 63;
    const int wave = tid >> 6;

    // stage X: coalesced fp32 loads, cvt to f16, swizzled 16B LDS writes
    const float* src = tokens + ((size_t)b * TOKSTRIDE + NC + r0) * EE;
    char* xbase = reinterpret_cast<char*>(Xs);
    #pragma unroll
    for (int i = 0; i < 8; ++i) {
        int pp  = i * 256 + tid;               // 16B-chunk index within 64x(32 chunks)
        int row = pp >> 5;
        int cp  = pp & 31;
        const float* s = src + (size_t)row * EE + cp * 8;
        float4 v0 = *reinterpret_cast<const float4*>(s);
        float4 v1 = *reinterpret_cast<const float4*>(s + 4);
        f16x8 h;
        h[0] = (_Float16)v0.x; h[1] = (_Float16)v0.y;
        h[2] = (_Float16)v0.z; h[3] = (_Float16)v0.w;
        h[4] = (_Float16)v1.x; h[5] = (_Float16)v1.y;
        h[6] = (_Float16)v1.z; h[7] = (_Float16)v1.w;
        *reinterpret_cast<f16x8*>(xbase + row * 512 + ((cp ^ (row & 7)) << 4)) = h;
    }

    // B fragments: whole Wf (256x16) as 8 k-tiles, loaded once per block.
    // lane holds B[k = kt*32 + (lane>>4)*8 + j][col = lane&15]
    const int col = lane & 15;
    const int kg  = lane >> 4;
    f16x8 bfrag[8];
    #pragma unroll
    for (int kt = 0; kt < 8; ++kt) {
        #pragma unroll
        for (int j = 0; j < 8; ++j) {
            int k = kt * 32 + kg * 8 + j;
            bfrag[kt][j] = (_Float16)Wf[k * 16 + col];
        }
    }
    __syncthreads();

    // MFMA: wave's 16x16 output tile, K=256.
    // A frag: lane holds A[row = wave*16 + (lane&15)][k = kt*32 + kg*8 + j]
    const int arow = wave * 16 + col;
    const char* xrow = xbase + arow * 512;
    const int swz = arow & 7;
    f32x4 acc = {0.f, 0.f, 0.f, 0.f};
    #pragma unroll
    for (int kt = 0; kt < 8; ++kt) {
        const int chunk = kt * 4 + kg;         // 16B chunk = 8 f16 = 8 k's
        f16x8 a = *reinterpret_cast<const f16x8*>(xrow + ((chunk ^ swz) << 4));
        acc = __builtin_amdgcn_mfma_f32_16x16x32_f16(a, bfrag[kt], acc, 0, 0, 0);
    }

    // store: D col = lane&15, row = (lane>>4)*4 + reg  (m89-verified layout)
    const float bias = bf[col];
    #pragma unroll
    for (int r = 0; r < 4; ++r) {
        int orow = r0 + wave * 16 + kg * 4 + r;
        patch[((size_t)b * NF + orow) * 16 + col] = acc[r] + bias;
    }
}

// ---------------- K4: fused scatter + conv + blend + downsample ----------------
struct InterpArgs { int i0[32]; int i1[32]; float fr[32]; };

__global__ __launch_bounds__(128) void k_out(const float* __restrict__ coarse_img,
                                             const float* __restrict__ patch,
                                             const int* __restrict__ mask,
                                             const int* __restrict__ cum,
                                             const float* __restrict__ noise,
                                             const float* __restrict__ convw,
                                             float* __restrict__ out,
                                             InterpArgs ia) {
    const int tid = blockIdx.x * 128 + threadIdx.x;   // 32768
    const int b = tid >> 10;
    const int p = (tid >> 5) & 31;
    const int q = tid & 31;

    float kk[9];
    #pragma unroll
    for (int i = 0; i < 9; ++i) kk[i] = convw[i];

    const int   hs[2]  = { ia.i0[p], ia.i1[p] };
    const float fh     = ia.fr[p];
    const float wh[2]  = { 1.f - fh, fh };
    const int   wsx[2] = { ia.i0[q], ia.i1[q] };
    const float fw     = ia.fr[q];
    const float ww[2]  = { 1.f - fw, fw };

    const float* cimg = coarse_img + (size_t)b*65536;
    const float* nimg = noise      + (size_t)b*65536;

    float acc = 0.f;
    #pragma unroll
    for (int a = 0; a < 2; ++a) {
        #pragma unroll
        for (int c = 0; c < 2; ++c) {
            const int h = hs[a], w = wsx[c];
            float conv = 0.f;
            #pragma unroll
            for (int dh = -1; dh <= 1; ++dh) {
                #pragma unroll
                for (int dw = -1; dw <= 1; ++dw) {
                    int hh = h + dh, wp = w + dw;
                    float v = (hh >= 0 && hh < IMG && wp >= 0 && wp < IMG)
                              ? cimg[hh*IMG + wp] : 0.f;
                    conv = fmaf(v, kk[(dh+1)*3 + (dw+1)], conv);
                }
            }
            const int j = (h >> 2) * 64 + (w >> 2);
            float fv = 0.f;
            if (mask[b*NF + j] != 0) {
                int rk  = cum[b*NF + j] - 1;
                int colx = (h & 3) * 4 + (w & 3);
                fv = patch[((size_t)b*NF + rk)*16 + colx];
            }
            float s = 1.f / (1.f + expf(-0.1f * nimg[h*IMG + w]));
            acc += wh[a] * ww[c] * (conv * (1.f - s) + fv * s);
        }
    }
    out[tid] = acc;
}

extern "C" void kernel_launch(void* const* d_in, const int* in_sizes, int n_in,
                              void* d_out, int out_size, void* d_ws, size_t ws_size,
                              hipStream_t stream) {
    const float* tokens = (const float*)d_in[0];
    const int*   mask   = (const int*)  d_in[1];
    const float* Wc     = (const float*)d_in[2];
    const float* bc     = (const float*)d_in[3];
    const float* Wf     = (const float*)d_in[4];
    const float* bf     = (const float*)d_in[5];
    const float* convw  = (const float*)d_in[6];
    const float* noise  = (const float*)d_in[7];

    float* ws = (float*)d_ws;
    float* coarse_img = ws;                               // 32*65536 floats
    float* patch      = ws + (size_t)BB*65536;            // 32*4096*16 floats
    int*   cum        = (int*)(ws + (size_t)2*BB*65536);  // 32*4096 ints

    k_scan  <<<32,   256, 0, stream>>>(mask, cum);
    k_coarse<<<1024, 256, 0, stream>>>(tokens, Wc, bc, coarse_img);
    k_gemm  <<<2048, 256, 0, stream>>>(tokens, cum, Wf, bf, patch);

    InterpArgs ia;
    for (int p = 0; p < 32; ++p) {
        double pos = (double)p * 255.0 / 31.0;
        int i0 = (int)floor(pos);
        int i1 = (i0 + 1 < 256) ? i0 + 1 : 255;
        ia.i0[p] = i0; ia.i1[p] = i1; ia.fr[p] = (float)(pos - (double)i0);
    }
    k_out<<<256, 128, 0, stream>>>(coarse_img, patch, mask, cum, noise, convw,
                                   (float*)d_out, ia);
}

// Round 8
// 37.870 us; speedup vs baseline: 2.9988x; 1.4527x over previous
//
#include <hip/hip_runtime.h>
#include <cmath>

// Problem constants (fixed by setup_inputs)
#define BB 32
#define EE 256
#define NC 1024
#define NF 4096
#define TOKSTRIDE 5120   // Nc+Nf rows per batch
#define IMG 256

typedef _Float16 f16x8 __attribute__((ext_vector_type(8)));
typedef float    f32x4 __attribute__((ext_vector_type(4)));

// Stage 64 rows x 256 fp32 -> f16 into LDS (32 KB). 16B-chunk index XORed
// with (row&7) -- the SAME involution is applied on the read side.
__device__ __forceinline__ void stage64_f16(const float* __restrict__ src,
                                            char* __restrict__ xbase, int tid) {
    #pragma unroll
    for (int i = 0; i < 8; ++i) {
        int pp  = i * 256 + tid;               // 16B-chunk index within 64x32
        int row = pp >> 5;
        int cp  = pp & 31;
        const float* s = src + (size_t)row * EE + cp * 8;
        float4 v0 = *reinterpret_cast<const float4*>(s);
        float4 v1 = *reinterpret_cast<const float4*>(s + 4);
        f16x8 h;
        h[0] = (_Float16)v0.x; h[1] = (_Float16)v0.y;
        h[2] = (_Float16)v0.z; h[3] = (_Float16)v0.w;
        h[4] = (_Float16)v1.x; h[5] = (_Float16)v1.y;
        h[6] = (_Float16)v1.z; h[7] = (_Float16)v1.w;
        *reinterpret_cast<f16x8*>(xbase + row * 512 + ((cp ^ (row & 7)) << 4)) = h;
    }
}

// ---------------- K1: coarse GEMM via f16 MFMA ----------------
// Block: 64 tokens x 64 cols. Wave w = col-tile (16 cols), 4 M-tiles of 16 rows.
// Same fragment mapping as k_gemm (validated on HW in round 7).
__global__ __launch_bounds__(256) void k_coarse(const float* __restrict__ tokens,
                                                const float* __restrict__ Wc,
                                                const float* __restrict__ bc,
                                                float* __restrict__ coarse_img) {
    const int b  = blockIdx.x >> 4;            // 16 tiles/batch
    const int t0 = (blockIdx.x & 15) * 64;

    __shared__ _Float16 Xs[64 * 256];          // 32 KB
    const int tid  = threadIdx.x;
    const int lane = tid & 63;
    const int wave = tid >> 6;
    char* xbase = reinterpret_cast<char*>(Xs);

    stage64_f16(tokens + ((size_t)b * TOKSTRIDE + t0) * EE, xbase, tid);

    // B fragments from Wc (256x64): wave covers cols c0..c0+15.
    // lane holds B[k = kt*32 + (lane>>4)*8 + j][col = c0 + (lane&15)]
    const int colg = lane & 15;
    const int kg   = lane >> 4;
    const int c0   = wave * 16;
    f16x8 bfrag[8];
    #pragma unroll
    for (int kt = 0; kt < 8; ++kt) {
        #pragma unroll
        for (int j = 0; j < 8; ++j) {
            int k = kt * 32 + kg * 8 + j;
            bfrag[kt][j] = (_Float16)Wc[k * 64 + c0 + colg];
        }
    }
    __syncthreads();

    f32x4 acc[4];
    #pragma unroll
    for (int mt = 0; mt < 4; ++mt) acc[mt] = (f32x4){0.f, 0.f, 0.f, 0.f};

    #pragma unroll
    for (int kt = 0; kt < 8; ++kt) {
        #pragma unroll
        for (int mt = 0; mt < 4; ++mt) {
            const int arow = mt * 16 + colg;
            const int chunk = kt * 4 + kg;
            f16x8 a = *reinterpret_cast<const f16x8*>(
                xbase + arow * 512 + ((chunk ^ (arow & 7)) << 4));
            acc[mt] = __builtin_amdgcn_mfma_f32_16x16x32_f16(a, bfrag[kt], acc[mt], 0, 0, 0);
        }
    }

    // D: col = lane&15, row(within tile) = kg*4 + r. Scatter to 8x8 patch grid.
    const int col  = c0 + colg;
    const float bias = bc[col];
    const int ph = col >> 3, pw = col & 7;
    #pragma unroll
    for (int mt = 0; mt < 4; ++mt) {
        #pragma unroll
        for (int r = 0; r < 4; ++r) {
            int tg = t0 + mt * 16 + kg * 4 + r;
            int hc = tg >> 5, wc = tg & 31;
            coarse_img[(size_t)b * 65536 + (hc * 8 + ph) * 256 + wc * 8 + pw]
                = acc[mt][r] + bias;
        }
    }
}

// ---------------- K2: per-batch inclusive cumsum of mask ----------------
__global__ __launch_bounds__(256) void k_scan(const int* __restrict__ mask,
                                              int* __restrict__ cum) {
    __shared__ int sums[256];
    const int b = blockIdx.x;
    const int tid = threadIdx.x;
    const int* m = mask + b * NF;

    int loc[16];
    int s = 0;
    #pragma unroll
    for (int i = 0; i < 16; ++i) { int v = (m[tid*16 + i] != 0) ? 1 : 0; s += v; loc[i] = s; }
    sums[tid] = s;
    __syncthreads();

    for (int off = 1; off < 256; off <<= 1) {
        int v = sums[tid];
        int add = (tid >= off) ? sums[tid - off] : 0;
        __syncthreads();
        sums[tid] = v + add;
        __syncthreads();
    }
    int excl = sums[tid] - s;
    #pragma unroll
    for (int i = 0; i < 16; ++i) cum[b*NF + tid*16 + i] = excl + loc[i];
}

// ---------------- K3: fine GEMM via f16 MFMA over compacted rows ----------------
__global__ __launch_bounds__(256) void k_gemm(const float* __restrict__ tokens,
                                              const int* __restrict__ cum,
                                              const float* __restrict__ Wf,
                                              const float* __restrict__ bf,
                                              float* __restrict__ patch) {
    const int b  = blockIdx.x >> 6;            // 64 tiles/batch
    const int r0 = (blockIdx.x & 63) * 64;
    const int cnt = cum[b*NF + NF - 1];
    if (r0 >= cnt) return;

    __shared__ _Float16 Xs[64 * 256];          // 32 KB
    const int tid  = threadIdx.x;
    const int lane = tid & 63;
    const int wave = tid >> 6;
    char* xbase = reinterpret_cast<char*>(Xs);

    stage64_f16(tokens + ((size_t)b * TOKSTRIDE + NC + r0) * EE, xbase, tid);

    // B fragments: lane holds B[k = kt*32 + (lane>>4)*8 + j][col = lane&15]
    const int col = lane & 15;
    const int kg  = lane >> 4;
    f16x8 bfrag[8];
    #pragma unroll
    for (int kt = 0; kt < 8; ++kt) {
        #pragma unroll
        for (int j = 0; j < 8; ++j) {
            int k = kt * 32 + kg * 8 + j;
            bfrag[kt][j] = (_Float16)Wf[k * 16 + col];
        }
    }
    __syncthreads();

    // MFMA: wave's 16x16 output tile, K=256.
    const int arow = wave * 16 + col;
    const char* xrow = xbase + arow * 512;
    const int swz = arow & 7;
    f32x4 acc = {0.f, 0.f, 0.f, 0.f};
    #pragma unroll
    for (int kt = 0; kt < 8; ++kt) {
        const int chunk = kt * 4 + kg;
        f16x8 a = *reinterpret_cast<const f16x8*>(xrow + ((chunk ^ swz) << 4));
        acc = __builtin_amdgcn_mfma_f32_16x16x32_f16(a, bfrag[kt], acc, 0, 0, 0);
    }

    // store: D col = lane&15, row = (lane>>4)*4 + reg
    const float bias = bf[col];
    #pragma unroll
    for (int r = 0; r < 4; ++r) {
        int orow = r0 + wave * 16 + kg * 4 + r;
        patch[((size_t)b * NF + orow) * 16 + col] = acc[r] + bias;
    }
}

// ---------------- K4: fused scatter + conv + blend + downsample ----------------
struct InterpArgs { int i0[32]; int i1[32]; float fr[32]; };

__global__ __launch_bounds__(128) void k_out(const float* __restrict__ coarse_img,
                                             const float* __restrict__ patch,
                                             const int* __restrict__ mask,
                                             const int* __restrict__ cum,
                                             const float* __restrict__ noise,
                                             const float* __restrict__ convw,
                                             float* __restrict__ out,
                                             InterpArgs ia) {
    const int tid = blockIdx.x * 128 + threadIdx.x;   // 32768
    const int b = tid >> 10;
    const int p = (tid >> 5) & 31;
    const int q = tid & 31;

    float kk[9];
    #pragma unroll
    for (int i = 0; i < 9; ++i) kk[i] = convw[i];

    const int   hs[2]  = { ia.i0[p], ia.i1[p] };
    const float fh     = ia.fr[p];
    const float wh[2]  = { 1.f - fh, fh };
    const int   wsx[2] = { ia.i0[q], ia.i1[q] };
    const float fw     = ia.fr[q];
    const float ww[2]  = { 1.f - fw, fw };

    const float* cimg = coarse_img + (size_t)b*65536;
    const float* nimg = noise      + (size_t)b*65536;

    float acc = 0.f;
    #pragma unroll
    for (int a = 0; a < 2; ++a) {
        #pragma unroll
        for (int c = 0; c < 2; ++c) {
            const int h = hs[a], w = wsx[c];
            float conv = 0.f;
            #pragma unroll
            for (int dh = -1; dh <= 1; ++dh) {
                #pragma unroll
                for (int dw = -1; dw <= 1; ++dw) {
                    int hh = h + dh, wp = w + dw;
                    float v = (hh >= 0 && hh < IMG && wp >= 0 && wp < IMG)
                              ? cimg[hh*IMG + wp] : 0.f;
                    conv = fmaf(v, kk[(dh+1)*3 + (dw+1)], conv);
                }
            }
            const int j = (h >> 2) * 64 + (w >> 2);
            float fv = 0.f;
            if (mask[b*NF + j] != 0) {
                int rk  = cum[b*NF + j] - 1;
                int colx = (h & 3) * 4 + (w & 3);
                fv = patch[((size_t)b*NF + rk)*16 + colx];
            }
            float s = 1.f / (1.f + expf(-0.1f * nimg[h*IMG + w]));
            acc += wh[a] * ww[c] * (conv * (1.f - s) + fv * s);
        }
    }
    out[tid] = acc;
}

extern "C" void kernel_launch(void* const* d_in, const int* in_sizes, int n_in,
                              void* d_out, int out_size, void* d_ws, size_t ws_size,
                              hipStream_t stream) {
    const float* tokens = (const float*)d_in[0];
    const int*   mask   = (const int*)  d_in[1];
    const float* Wc     = (const float*)d_in[2];
    const float* bc     = (const float*)d_in[3];
    const float* Wf     = (const float*)d_in[4];
    const float* bf     = (const float*)d_in[5];
    const float* convw  = (const float*)d_in[6];
    const float* noise  = (const float*)d_in[7];

    float* ws = (float*)d_ws;
    float* coarse_img = ws;                               // 32*65536 floats
    float* patch      = ws + (size_t)BB*65536;            // 32*4096*16 floats
    int*   cum        = (int*)(ws + (size_t)2*BB*65536);  // 32*4096 ints

    k_scan  <<<32,  256, 0, stream>>>(mask, cum);
    k_coarse<<<512, 256, 0, stream>>>(tokens, Wc, bc, coarse_img);
    k_gemm  <<<2048,256, 0, stream>>>(tokens, cum, Wf, bf, patch);

    InterpArgs ia;
    for (int p = 0; p < 32; ++p) {
        double pos = (double)p * 255.0 / 31.0;
        int i0 = (int)floor(pos);
        int i1 = (i0 + 1 < 256) ? i0 + 1 : 255;
        ia.i0[p] = i0; ia.i1[p] = i1; ia.fr[p] = (float)(pos - (double)i0);
    }
    k_out<<<256, 128, 0, stream>>>(coarse_img, patch, mask, cum, noise, convw,
                                   (float*)d_out, ia);
}

// Round 9
// 32.202 us; speedup vs baseline: 3.5267x; 1.1760x over previous
//
#include <hip/hip_runtime.h>
#include <cmath>

// Problem constants (fixed by setup_inputs)
#define BB 32
#define EE 256
#define NC 1024
#define NF 4096
#define TOKSTRIDE 5120   // Nc+Nf rows per batch
#define IMG 256

typedef _Float16 f16x8 __attribute__((ext_vector_type(8)));
typedef float    f32x4 __attribute__((ext_vector_type(4)));

// Stage 64 rows x 256 fp32 -> f16 into LDS (32 KB). 16B-chunk index XORed
// with (row&7) -- the SAME involution is applied on the read side.
__device__ __forceinline__ void stage64_f16(const float* __restrict__ src,
                                            char* __restrict__ xbase, int tid) {
    #pragma unroll
    for (int i = 0; i < 8; ++i) {
        int pp  = i * 256 + tid;               // 16B-chunk index within 64x32
        int row = pp >> 5;
        int cp  = pp & 31;
        const float* s = src + (size_t)row * EE + cp * 8;
        float4 v0 = *reinterpret_cast<const float4*>(s);
        float4 v1 = *reinterpret_cast<const float4*>(s + 4);
        f16x8 h;
        h[0] = (_Float16)v0.x; h[1] = (_Float16)v0.y;
        h[2] = (_Float16)v0.z; h[3] = (_Float16)v0.w;
        h[4] = (_Float16)v1.x; h[5] = (_Float16)v1.y;
        h[6] = (_Float16)v1.z; h[7] = (_Float16)v1.w;
        *reinterpret_cast<f16x8*>(xbase + row * 512 + ((cp ^ (row & 7)) << 4)) = h;
    }
}

// ---------------- K2: per-batch inclusive cumsum of mask ----------------
__global__ __launch_bounds__(256) void k_scan(const int* __restrict__ mask,
                                              int* __restrict__ cum) {
    __shared__ int sums[256];
    const int b = blockIdx.x;
    const int tid = threadIdx.x;
    const int* m = mask + b * NF;

    int loc[16];
    int s = 0;
    #pragma unroll
    for (int i = 0; i < 16; ++i) { int v = (m[tid*16 + i] != 0) ? 1 : 0; s += v; loc[i] = s; }
    sums[tid] = s;
    __syncthreads();

    for (int off = 1; off < 256; off <<= 1) {
        int v = sums[tid];
        int add = (tid >= off) ? sums[tid - off] : 0;
        __syncthreads();
        sums[tid] = v + add;
        __syncthreads();
    }
    int excl = sums[tid] - s;
    #pragma unroll
    for (int i = 0; i < 16; ++i) cum[b*NF + tid*16 + i] = excl + loc[i];
}

// ---------------- K13: fused coarse GEMM + fine GEMM (role by blockIdx) ----------------
// blocks [0,512): coarse -- 64 tokens x 64 cols; wave = 16-col tile, 4 M-tiles.
// blocks [512,2560): fine -- 64 compacted rows x 16 cols; wave = 16-row M-tile.
__global__ __launch_bounds__(256) void k_mm(const float* __restrict__ tokens,
                                            const float* __restrict__ Wc,
                                            const float* __restrict__ bc,
                                            const float* __restrict__ Wf,
                                            const float* __restrict__ bf,
                                            const int* __restrict__ cum,
                                            float* __restrict__ coarse_img,
                                            float* __restrict__ patch) {
    __shared__ _Float16 Xs[64 * 256];          // 32 KB
    const int tid  = threadIdx.x;
    const int lane = tid & 63;
    const int wave = tid >> 6;
    char* xbase = reinterpret_cast<char*>(Xs);
    const int colg = lane & 15;
    const int kg   = lane >> 4;

    if (blockIdx.x < 512) {
        // ---- coarse role ----
        const int b  = blockIdx.x >> 4;        // 16 tiles/batch
        const int t0 = (blockIdx.x & 15) * 64;

        stage64_f16(tokens + ((size_t)b * TOKSTRIDE + t0) * EE, xbase, tid);

        const int c0 = wave * 16;
        f16x8 bfrag[8];
        #pragma unroll
        for (int kt = 0; kt < 8; ++kt) {
            #pragma unroll
            for (int j = 0; j < 8; ++j) {
                int k = kt * 32 + kg * 8 + j;
                bfrag[kt][j] = (_Float16)Wc[k * 64 + c0 + colg];
            }
        }
        __syncthreads();

        f32x4 acc[4];
        #pragma unroll
        for (int mt = 0; mt < 4; ++mt) acc[mt] = (f32x4){0.f, 0.f, 0.f, 0.f};

        #pragma unroll
        for (int kt = 0; kt < 8; ++kt) {
            #pragma unroll
            for (int mt = 0; mt < 4; ++mt) {
                const int arow = mt * 16 + colg;
                const int chunk = kt * 4 + kg;
                f16x8 a = *reinterpret_cast<const f16x8*>(
                    xbase + arow * 512 + ((chunk ^ (arow & 7)) << 4));
                acc[mt] = __builtin_amdgcn_mfma_f32_16x16x32_f16(a, bfrag[kt], acc[mt], 0, 0, 0);
            }
        }

        const int col  = c0 + colg;
        const float bias = bc[col];
        const int ph = col >> 3, pw = col & 7;
        #pragma unroll
        for (int mt = 0; mt < 4; ++mt) {
            #pragma unroll
            for (int r = 0; r < 4; ++r) {
                int tg = t0 + mt * 16 + kg * 4 + r;
                int hc = tg >> 5, wc = tg & 31;
                coarse_img[(size_t)b * 65536 + (hc * 8 + ph) * 256 + wc * 8 + pw]
                    = acc[mt][r] + bias;
            }
        }
    } else {
        // ---- fine role ----
        const int u  = blockIdx.x - 512;
        const int b  = u >> 6;                 // 64 tiles/batch
        const int r0 = (u & 63) * 64;
        const int cnt = cum[b*NF + NF - 1];
        if (r0 >= cnt) return;

        stage64_f16(tokens + ((size_t)b * TOKSTRIDE + NC + r0) * EE, xbase, tid);

        f16x8 bfrag[8];
        #pragma unroll
        for (int kt = 0; kt < 8; ++kt) {
            #pragma unroll
            for (int j = 0; j < 8; ++j) {
                int k = kt * 32 + kg * 8 + j;
                bfrag[kt][j] = (_Float16)Wf[k * 16 + colg];
            }
        }
        __syncthreads();

        const int arow = wave * 16 + colg;
        const char* xrow = xbase + arow * 512;
        const int swz = arow & 7;
        f32x4 acc = {0.f, 0.f, 0.f, 0.f};
        #pragma unroll
        for (int kt = 0; kt < 8; ++kt) {
            const int chunk = kt * 4 + kg;
            f16x8 a = *reinterpret_cast<const f16x8*>(xrow + ((chunk ^ swz) << 4));
            acc = __builtin_amdgcn_mfma_f32_16x16x32_f16(a, bfrag[kt], acc, 0, 0, 0);
        }

        const float bias = bf[colg];
        #pragma unroll
        for (int r = 0; r < 4; ++r) {
            int orow = r0 + wave * 16 + kg * 4 + r;
            patch[((size_t)b * NF + orow) * 16 + colg] = acc[r] + bias;
        }
    }
}

// ---------------- K4: fused scatter + conv + blend + downsample ----------------
// 4 lanes per output pixel (one per bilinear corner), shfl reduce.
struct InterpArgs { int i0[32]; int i1[32]; float fr[32]; };

__global__ __launch_bounds__(256) void k_out(const float* __restrict__ coarse_img,
                                             const float* __restrict__ patch,
                                             const int* __restrict__ mask,
                                             const int* __restrict__ cum,
                                             const float* __restrict__ noise,
                                             const float* __restrict__ convw,
                                             float* __restrict__ out,
                                             InterpArgs ia) {
    const int gt = blockIdx.x * 256 + threadIdx.x;    // 131072 threads
    const int o  = gt >> 2;                           // output index 0..32767
    const int corner = gt & 3;
    const int a = corner >> 1, c = corner & 1;

    const int b = o >> 10;
    const int p = (o >> 5) & 31;
    const int q = o & 31;

    float kk[9];
    #pragma unroll
    for (int i = 0; i < 9; ++i) kk[i] = convw[i];

    const int   h  = a ? ia.i1[p] : ia.i0[p];
    const int   w  = c ? ia.i1[q] : ia.i0[q];
    const float fh = ia.fr[p], fw = ia.fr[q];
    const float wt = (a ? fh : 1.f - fh) * (c ? fw : 1.f - fw);

    const float* cimg = coarse_img + (size_t)b*65536;
    const float* nimg = noise      + (size_t)b*65536;

    float conv = 0.f;
    #pragma unroll
    for (int dh = -1; dh <= 1; ++dh) {
        #pragma unroll
        for (int dw = -1; dw <= 1; ++dw) {
            int hh = h + dh, wp = w + dw;
            float v = (hh >= 0 && hh < IMG && wp >= 0 && wp < IMG)
                      ? cimg[hh*IMG + wp] : 0.f;
            conv = fmaf(v, kk[(dh+1)*3 + (dw+1)], conv);
        }
    }
    const int j = (h >> 2) * 64 + (w >> 2);
    float fv = 0.f;
    if (mask[b*NF + j] != 0) {
        int rk  = cum[b*NF + j] - 1;
        int colx = (h & 3) * 4 + (w & 3);
        fv = patch[((size_t)b*NF + rk)*16 + colx];
    }
    float s = 1.f / (1.f + expf(-0.1f * nimg[h*IMG + w]));
    float val = wt * (conv * (1.f - s) + fv * s);

    val += __shfl_xor(val, 1, 64);
    val += __shfl_xor(val, 2, 64);
    if (corner == 0) out[o] = val;
}

extern "C" void kernel_launch(void* const* d_in, const int* in_sizes, int n_in,
                              void* d_out, int out_size, void* d_ws, size_t ws_size,
                              hipStream_t stream) {
    const float* tokens = (const float*)d_in[0];
    const int*   mask   = (const int*)  d_in[1];
    const float* Wc     = (const float*)d_in[2];
    const float* bc     = (const float*)d_in[3];
    const float* Wf     = (const float*)d_in[4];
    const float* bf     = (const float*)d_in[5];
    const float* convw  = (const float*)d_in[6];
    const float* noise  = (const float*)d_in[7];

    float* ws = (float*)d_ws;
    float* coarse_img = ws;                               // 32*65536 floats
    float* patch      = ws + (size_t)BB*65536;            // 32*4096*16 floats
    int*   cum        = (int*)(ws + (size_t)2*BB*65536);  // 32*4096 ints

    k_scan<<<32,   256, 0, stream>>>(mask, cum);
    k_mm  <<<2560, 256, 0, stream>>>(tokens, Wc, bc, Wf, bf, cum,
                                     coarse_img, patch);

    InterpArgs ia;
    for (int p = 0; p < 32; ++p) {
        double pos = (double)p * 255.0 / 31.0;
        int i0 = (int)floor(pos);
        int i1 = (i0 + 1 < 256) ? i0 + 1 : 255;
        ia.i0[p] = i0; ia.i1[p] = i1; ia.fr[p] = (float)(pos - (double)i0);
    }
    k_out<<<512, 256, 0, stream>>>(coarse_img, patch, mask, cum, noise, convw,
                                   (float*)d_out, ia);
}

// Round 10
// 28.474 us; speedup vs baseline: 3.9884x; 1.1309x over previous
//
#include <hip/hip_runtime.h>
#include <cmath>

// Problem constants (fixed by setup_inputs)
#define BB 32
#define EE 256
#define NC 1024
#define NF 4096
#define TOKSTRIDE 5120   // Nc+Nf rows per batch
#define IMG 256
#define MAXHF 64

typedef _Float16 f16x8 __attribute__((ext_vector_type(8)));
typedef _Float16 f16x4 __attribute__((ext_vector_type(4)));
typedef float    f32x4 __attribute__((ext_vector_type(4)));

struct SampArgs {
    int i0[32]; int i1[32]; float fr[32];
    int hfl[MAXHF];   // needed hf values (sorted), nhf entries
    int inv[64];      // hf -> dense index in hfl
    int nhf, nj, jblocks;
};

// ---------------- K2: per-batch inclusive cumsum of mask ----------------
__global__ __launch_bounds__(256) void k_scan(const int* __restrict__ mask,
                                              int* __restrict__ cum) {
    __shared__ int sums[256];
    const int b = blockIdx.x;
    const int tid = threadIdx.x;
    const int* m = mask + b * NF;

    int loc[16];
    int s = 0;
    #pragma unroll
    for (int i = 0; i < 16; ++i) { int v = (m[tid*16 + i] != 0) ? 1 : 0; s += v; loc[i] = s; }
    sums[tid] = s;
    __syncthreads();

    for (int off = 1; off < 256; off <<= 1) {
        int v = sums[tid];
        int add = (tid >= off) ? sums[tid - off] : 0;
        __syncthreads();
        sums[tid] = v + add;
        __syncthreads();
    }
    int excl = sums[tid] - s;
    #pragma unroll
    for (int i = 0; i < 16; ++i) cum[b*NF + tid*16 + i] = excl + loc[i];
}

// ---------------- K13: fused coarse GEMM + sparse fine gather-GEMM ----------------
// blocks [0,512): coarse role (dense, 64 tokens x 64 cols).
// blocks [512, 512+32*jblocks): fine role -- 64 needed-j's per block, gathered
// token rows, output patch_j[b][u][16] (zeros for unmasked).
__global__ __launch_bounds__(256) void k_mm(const float* __restrict__ tokens,
                                            const float* __restrict__ Wc,
                                            const float* __restrict__ bc,
                                            const float* __restrict__ Wf,
                                            const float* __restrict__ bf,
                                            const int* __restrict__ mask,
                                            const int* __restrict__ cum,
                                            float* __restrict__ coarse_img,
                                            float* __restrict__ patch_j,
                                            SampArgs sa) {
    __shared__ _Float16 Xs[64 * 256];          // 32 KB
    __shared__ int rowsrc[64];
    const int tid  = threadIdx.x;
    const int lane = tid & 63;
    const int wave = tid >> 6;
    char* xbase = reinterpret_cast<char*>(Xs);
    const int colg = lane & 15;
    const int kg   = lane >> 4;

    if (blockIdx.x < 512) {
        // ---- coarse role: dense 64-token tile ----
        const int b  = blockIdx.x >> 4;
        const int t0 = (blockIdx.x & 15) * 64;

        const float* src = tokens + ((size_t)b * TOKSTRIDE + t0) * EE;
        #pragma unroll
        for (int i = 0; i < 8; ++i) {
            int pp  = i * 256 + tid;
            int row = pp >> 5;
            int cp  = pp & 31;
            const float* s = src + (size_t)row * EE + cp * 8;
            float4 v0 = *reinterpret_cast<const float4*>(s);
            float4 v1 = *reinterpret_cast<const float4*>(s + 4);
            f16x8 h;
            h[0] = (_Float16)v0.x; h[1] = (_Float16)v0.y;
            h[2] = (_Float16)v0.z; h[3] = (_Float16)v0.w;
            h[4] = (_Float16)v1.x; h[5] = (_Float16)v1.y;
            h[6] = (_Float16)v1.z; h[7] = (_Float16)v1.w;
            *reinterpret_cast<f16x8*>(xbase + row * 512 + ((cp ^ (row & 7)) << 4)) = h;
        }

        const int c0 = wave * 16;
        f16x8 bfrag[8];
        #pragma unroll
        for (int kt = 0; kt < 8; ++kt) {
            #pragma unroll
            for (int j = 0; j < 8; ++j) {
                int k = kt * 32 + kg * 8 + j;
                bfrag[kt][j] = (_Float16)Wc[k * 64 + c0 + colg];
            }
        }
        __syncthreads();

        f32x4 acc[4];
        #pragma unroll
        for (int mt = 0; mt < 4; ++mt) acc[mt] = (f32x4){0.f, 0.f, 0.f, 0.f};

        #pragma unroll
        for (int kt = 0; kt < 8; ++kt) {
            #pragma unroll
            for (int mt = 0; mt < 4; ++mt) {
                const int arow = mt * 16 + colg;
                const int chunk = kt * 4 + kg;
                f16x8 a = *reinterpret_cast<const f16x8*>(
                    xbase + arow * 512 + ((chunk ^ (arow & 7)) << 4));
                acc[mt] = __builtin_amdgcn_mfma_f32_16x16x32_f16(a, bfrag[kt], acc[mt], 0, 0, 0);
            }
        }

        const int col  = c0 + colg;
        const float bias = bc[col];
        const int ph = col >> 3, pw = col & 7;
        #pragma unroll
        for (int mt = 0; mt < 4; ++mt) {
            #pragma unroll
            for (int r = 0; r < 4; ++r) {
                int tg = t0 + mt * 16 + kg * 4 + r;
                int hc = tg >> 5, wc = tg & 31;
                coarse_img[(size_t)b * 65536 + (hc * 8 + ph) * 256 + wc * 8 + pw]
                    = acc[mt][r] + bias;
            }
        }
    } else {
        // ---- fine role: 64 needed-j's, gathered rows ----
        const int u0blk = blockIdx.x - 512;
        const int b  = u0blk / sa.jblocks;
        const int u0 = (u0blk - b * sa.jblocks) * 64;

        if (tid < 64) {
            int u = u0 + tid;
            int ridx = -1;
            if (u < sa.nj) {
                int uh = u / sa.nhf;
                int uw = u - uh * sa.nhf;
                int j  = sa.hfl[uh] * 64 + sa.hfl[uw];
                if (mask[b * NF + j] != 0) ridx = cum[b * NF + j] - 1;
            }
            rowsrc[tid] = ridx;
        }
        __syncthreads();

        // stage gathered rows (4 rows/iter, 64 lanes x float4 per row)
        const int rgrp   = tid >> 6;
        const int lane64 = tid & 63;
        for (int it = 0; it < 16; ++it) {
            int rl = it * 4 + rgrp;
            int ridx = rowsrc[rl];
            int cp   = lane64 >> 1;            // 16B chunk
            int half = lane64 & 1;
            f16x4 hv = {0, 0, 0, 0};
            if (ridx >= 0) {
                const float* s = tokens + ((size_t)b * TOKSTRIDE + NC + ridx) * EE + lane64 * 4;
                float4 v = *reinterpret_cast<const float4*>(s);
                hv[0] = (_Float16)v.x; hv[1] = (_Float16)v.y;
                hv[2] = (_Float16)v.z; hv[3] = (_Float16)v.w;
            }
            *reinterpret_cast<f16x4*>(xbase + rl * 512 + (((cp ^ (rl & 7)) << 4) | (half << 3))) = hv;
        }

        f16x8 bfrag[8];
        #pragma unroll
        for (int kt = 0; kt < 8; ++kt) {
            #pragma unroll
            for (int j = 0; j < 8; ++j) {
                int k = kt * 32 + kg * 8 + j;
                bfrag[kt][j] = (_Float16)Wf[k * 16 + colg];
            }
        }
        __syncthreads();

        const int arow = wave * 16 + colg;
        const char* xrow = xbase + arow * 512;
        const int swz = arow & 7;
        f32x4 acc = {0.f, 0.f, 0.f, 0.f};
        #pragma unroll
        for (int kt = 0; kt < 8; ++kt) {
            const int chunk = kt * 4 + kg;
            f16x8 a = *reinterpret_cast<const f16x8*>(xrow + ((chunk ^ swz) << 4));
            acc = __builtin_amdgcn_mfma_f32_16x16x32_f16(a, bfrag[kt], acc, 0, 0, 0);
        }

        const float bias = bf[colg];
        #pragma unroll
        for (int r = 0; r < 4; ++r) {
            int ol = wave * 16 + kg * 4 + r;   // local u offset
            int u  = u0 + ol;
            if (u < sa.nj) {
                float v = (rowsrc[ol] >= 0) ? (acc[r] + bias) : 0.f;
                patch_j[((size_t)b * sa.nj + u) * 16 + colg] = v;
            }
        }
    }
}

// ---------------- K4: fused conv + blend + downsample (4 lanes/pixel) ----------------
__global__ __launch_bounds__(256) void k_out(const float* __restrict__ coarse_img,
                                             const float* __restrict__ patch_j,
                                             const float* __restrict__ noise,
                                             const float* __restrict__ convw,
                                             float* __restrict__ out,
                                             SampArgs sa) {
    const int gt = blockIdx.x * 256 + threadIdx.x;    // 131072 threads
    const int o  = gt >> 2;                           // output index 0..32767
    const int corner = gt & 3;
    const int a = corner >> 1, c = corner & 1;

    const int b = o >> 10;
    const int p = (o >> 5) & 31;
    const int q = o & 31;

    float kk[9];
    #pragma unroll
    for (int i = 0; i < 9; ++i) kk[i] = convw[i];

    const int   h  = a ? sa.i1[p] : sa.i0[p];
    const int   w  = c ? sa.i1[q] : sa.i0[q];
    const float fh = sa.fr[p], fw = sa.fr[q];
    const float wt = (a ? fh : 1.f - fh) * (c ? fw : 1.f - fw);

    const float* cimg = coarse_img + (size_t)b*65536;
    const float* nimg = noise      + (size_t)b*65536;

    float conv = 0.f;
    #pragma unroll
    for (int dh = -1; dh <= 1; ++dh) {
        #pragma unroll
        for (int dw = -1; dw <= 1; ++dw) {
            int hh = h + dh, wp = w + dw;
            float v = (hh >= 0 && hh < IMG && wp >= 0 && wp < IMG)
                      ? cimg[hh*IMG + wp] : 0.f;
            conv = fmaf(v, kk[(dh+1)*3 + (dw+1)], conv);
        }
    }
    const int jj = sa.inv[h >> 2] * sa.nhf + sa.inv[w >> 2];
    const int colx = (h & 3) * 4 + (w & 3);
    float fv = patch_j[((size_t)b * sa.nj + jj) * 16 + colx];

    float s = 1.f / (1.f + expf(-0.1f * nimg[h*IMG + w]));
    float val = wt * (conv * (1.f - s) + fv * s);

    val += __shfl_xor(val, 1, 64);
    val += __shfl_xor(val, 2, 64);
    if (corner == 0) out[o] = val;
}

extern "C" void kernel_launch(void* const* d_in, const int* in_sizes, int n_in,
                              void* d_out, int out_size, void* d_ws, size_t ws_size,
                              hipStream_t stream) {
    const float* tokens = (const float*)d_in[0];
    const int*   mask   = (const int*)  d_in[1];
    const float* Wc     = (const float*)d_in[2];
    const float* bc     = (const float*)d_in[3];
    const float* Wf     = (const float*)d_in[4];
    const float* bf     = (const float*)d_in[5];
    const float* convw  = (const float*)d_in[6];
    const float* noise  = (const float*)d_in[7];

    // interp + needed-hf structures (host, deterministic)
    SampArgs sa;
    bool need[64] = {false};
    for (int p = 0; p < 32; ++p) {
        double pos = (double)p * 255.0 / 31.0;
        int i0 = (int)floor(pos);
        int i1 = (i0 + 1 < 256) ? i0 + 1 : 255;
        sa.i0[p] = i0; sa.i1[p] = i1; sa.fr[p] = (float)(pos - (double)i0);
        need[i0 >> 2] = true; need[i1 >> 2] = true;
    }
    int nhf = 0;
    for (int hf = 0; hf < 64; ++hf) {
        sa.inv[hf] = 0;
        if (need[hf]) { sa.inv[hf] = nhf; sa.hfl[nhf++] = hf; }
    }
    for (int i = nhf; i < MAXHF; ++i) sa.hfl[i] = 0;
    sa.nhf = nhf;
    sa.nj  = nhf * nhf;
    sa.jblocks = (sa.nj + 63) / 64;

    float* ws = (float*)d_ws;
    float* coarse_img = ws;                               // 32*65536 floats
    float* patch_j    = ws + (size_t)BB*65536;            // 32*nj*16 floats (<= 32*4096*16)
    int*   cum        = (int*)(ws + (size_t)2*BB*65536);  // 32*4096 ints

    k_scan<<<32, 256, 0, stream>>>(mask, cum);
    k_mm  <<<512 + BB * sa.jblocks, 256, 0, stream>>>(tokens, Wc, bc, Wf, bf,
                                                      mask, cum, coarse_img,
                                                      patch_j, sa);
    k_out <<<512, 256, 0, stream>>>(coarse_img, patch_j, noise, convw,
                                    (float*)d_out, sa);
}